// Round 4
// baseline (525.081 us; speedup 1.0000x reference)
//
#include <hip/hip_runtime.h>
#include <hip/hip_bf16.h>

// LSTM block, fused, persistent-block streaming version.
// Inputs fp32, outputs fp32. bf16 MFMA internally.
// grid=256 x 512 threads; each block loops over 8 tiles of 128 rows.
// A: global->reg frags + cvt (no LDS). B: LDS dbuf via global_load_lds,
// counted-vmcnt barriers keep A-prefetch in flight across barriers (T3/T4).

typedef __attribute__((ext_vector_type(8))) short bf16x8;   // 8 bf16 = 4 VGPRs
typedef __attribute__((ext_vector_type(4))) float f32x4;

static __device__ __forceinline__ unsigned short f2bf(float f) {
    unsigned int u = __builtin_bit_cast(unsigned int, f);
    u += 0x7FFFu + ((u >> 16) & 1u);      // RNE
    return (unsigned short)(u >> 16);
}

static __device__ __forceinline__ bf16x8 cvt8(f32x4 a, f32x4 b) {
    union { bf16x8 v; unsigned short u[8]; } r;
    r.u[0] = f2bf(a[0]); r.u[1] = f2bf(a[1]); r.u[2] = f2bf(a[2]); r.u[3] = f2bf(a[3]);
    r.u[4] = f2bf(b[0]); r.u[5] = f2bf(b[1]); r.u[6] = f2bf(b[2]); r.u[7] = f2bf(b[3]);
    return r.v;
}

static __device__ __forceinline__ float fsig(float x) {
    float e = __builtin_amdgcn_exp2f(-1.44269504f * x);
    return __builtin_amdgcn_rcpf(1.0f + e);
}
static __device__ __forceinline__ float ftanh(float x) {
    float e = __builtin_amdgcn_exp2f(2.8853900818f * x);
    return 1.0f - 2.0f * __builtin_amdgcn_rcpf(e + 1.0f);
}

static __device__ __forceinline__ void gload16(const void* gsrc, void* ldst) {
    __builtin_amdgcn_global_load_lds(
        (const __attribute__((address_space(1))) unsigned int*)gsrc,
        (__attribute__((address_space(3))) unsigned int*)ldst,
        16, 0, 0);
}

#define MEMFENCE asm volatile("" ::: "memory")

// ---------------- weight prep: fragment-linear bf16 layouts (r3-proven) ----------------
__global__ void prep_weights(const float* __restrict__ Wf, const float* __restrict__ Wi,
                             const float* __restrict__ Wc, const float* __restrict__ Wo,
                             const float* __restrict__ Wch,
                             unsigned short* __restrict__ WgF,   // 512*256
                             unsigned short* __restrict__ WchF)  // 128*128
{
    int u = blockIdx.x * 256 + threadIdx.x;
    if (u < 16384) {
        int lane = u & 63, nb = (u >> 6) & 31, kc = u >> 11;
        int l15 = lane & 15, lg = lane >> 4;
        int np = nb * 16 + l15;                  // permuted col index
        int wv = np >> 7, g = (np >> 5) & 3, c5 = np & 31;
        int cg = wv * 32 + c5;                   // within-gate col
        int k0 = kc * 32 + lg * 8;
        const float* W = (g == 0) ? Wf : (g == 1) ? Wi : (g == 2) ? Wc : Wo;
        union { bf16x8 v; unsigned short s[8]; } r;
#pragma unroll
        for (int i = 0; i < 8; ++i) r.s[i] = f2bf(W[(size_t)(k0 + i) * 128 + cg]);
        *(bf16x8*)(WgF + (size_t)u * 8) = r.v;
    } else if (u < 16384 + 2048) {
        int u2 = u - 16384;
        int lane = u2 & 63, kt = (u2 >> 6) & 3, nb2 = u2 >> 8;
        int l15 = lane & 15, lg = lane >> 4;
        int n = nb2 * 16 + l15, k0 = kt * 32 + lg * 8;
        union { bf16x8 v; unsigned short s[8]; } r;
#pragma unroll
        for (int i = 0; i < 8; ++i) r.s[i] = f2bf(Wch[(size_t)(k0 + i) * 128 + n]);
        *(bf16x8*)(WchF + (size_t)u2 * 8) = r.v;
    }
}

// ---------------- fused persistent kernel ----------------
// LDS map (128 KB): B0 [0,32K) ; B1 [32K,64K) ; Wch [64K,96K) ; c_ex [96K,128K)
__global__ __launch_bounds__(512, 2) void lstm_fused(
    const float* __restrict__ xg, const float* __restrict__ hg, const float* __restrict__ cg,
    const float* __restrict__ bfv, const float* __restrict__ biv,
    const float* __restrict__ bcv, const float* __restrict__ bov,
    const float* __restrict__ bchv,
    const unsigned short* __restrict__ WgF, const unsigned short* __restrict__ WchF,
    float* __restrict__ out, int nrows)
{
    __shared__ uint4 lds4[8192];                 // 128 KB
    char* lds = (char*)lds4;

    const int tid  = threadIdx.x;
    const int lane = tid & 63;
    const int wv   = tid >> 6;                   // 0..7
    const int wm   = wv & 1;                     // row half (64 rows)
    const int wn   = wv >> 1;                    // col group (128 of 512)
    const int l15  = lane & 15;
    const int lg   = lane >> 4;
    const int tiles = nrows >> 15;               // nrows / (256*128) = 8
    const long base = (long)blockIdx.x * (long)tiles * 128;

    float* hout = out;
    float* cout = out + (size_t)nrows * 128;

    // biases (lane-local cols)
    float bfb[2], bib[2], bcb[2], bob[2], bchb[2];
#pragma unroll
    for (int hb = 0; hb < 2; ++hb) {
        int col = wn * 32 + hb * 16 + l15;
        bfb[hb] = bfv[col]; bib[hb] = biv[col]; bcb[hb] = bcv[col];
        bob[hb] = bov[col]; bchb[hb] = bchv[col];
    }

    // ---- prologue: stage Wch (once) + B chunk0; issue A-loads for step 0
#pragma unroll
    for (int j = 0; j < 4; ++j)
        gload16((const char*)WchF + j * 8192 + tid * 16, lds + 65536 + j * 8192 + tid * 16);
#pragma unroll
    for (int j = 0; j < 4; ++j)
        gload16((const char*)WgF + j * 8192 + tid * 16, lds + j * 8192 + tid * 16);
    MEMFENCE;

    f32x4 araw[2][4][2];
#pragma unroll
    for (int am = 0; am < 4; ++am) {
        long row = base + wm * 64 + am * 16 + l15;
        const f32x4* s = (const f32x4*)(xg + row * 128 + lg * 8);   // kc=0 -> x
        araw[0][am][0] = s[0];
        araw[0][am][1] = s[1];
    }
    asm volatile("s_waitcnt vmcnt(8)" ::: "memory");   // Wch+B0 landed; A0 in flight
    __builtin_amdgcn_s_barrier();

    f32x4 acc[4][8];
#pragma unroll
    for (int a = 0; a < 4; ++a)
#pragma unroll
        for (int b = 0; b < 8; ++b) acc[a][b] = {0.f, 0.f, 0.f, 0.f};

    float creg[4][2][4];

    for (int t = 0; t < tiles; ++t) {
        const long m0 = base + (long)t * 128;
#pragma unroll
        for (int kc = 0; kc < 8; ++kc) {
            const int cur = kc & 1, nxt = cur ^ 1;
            // c-input loads (issued first at kc==6 so every barrier is vmcnt(8))
            if (kc == 6) {
#pragma unroll
                for (int am = 0; am < 4; ++am)
#pragma unroll
                    for (int hb = 0; hb < 2; ++hb)
#pragma unroll
                        for (int r = 0; r < 4; ++r) {
                            long grow = m0 + wm * 64 + am * 16 + lg * 4 + r;
                            creg[am][hb][r] = cg[grow * 128 + wn * 32 + hb * 16 + l15];
                        }
                MEMFENCE;
            }
            // B prefetch: chunk (kc+1)&7 -> buf nxt
            {
                const char* src = (const char*)WgF + (size_t)((kc + 1) & 7) * 32768;
                char* dst = lds + nxt * 32768;
#pragma unroll
                for (int j = 0; j < 4; ++j)
                    gload16(src + j * 8192 + tid * 16, dst + j * 8192 + tid * 16);
            }
            MEMFENCE;
            // A loads for next step (last 8 vmem ops before the barrier)
            {
                int t1  = (kc == 7) ? ((t < tiles - 1) ? t + 1 : t) : t;
                int kc1 = (kc + 1) & 7;
                long m1 = base + (long)t1 * 128;
                int col = kc1 * 32 + lg * 8;
                const float* gsrc = (col < 128) ? (xg + col) : (hg + (col - 128));
#pragma unroll
                for (int am = 0; am < 4; ++am) {
                    long row = m1 + wm * 64 + am * 16 + l15;
                    const f32x4* s = (const f32x4*)(gsrc + row * 128);
                    araw[nxt][am][0] = s[0];
                    araw[nxt][am][1] = s[1];
                }
            }
            MEMFENCE;
            // cvt current A + MFMA against LDS B
            bf16x8 af[4];
#pragma unroll
            for (int am = 0; am < 4; ++am)
                af[am] = cvt8(araw[cur][am][0], araw[cur][am][1]);
            const char* bb = lds + cur * 32768 + wn * 8192;
#pragma unroll
            for (int bn = 0; bn < 8; ++bn) {
                bf16x8 bfr = *(const bf16x8*)(bb + bn * 1024 + lane * 16);
#pragma unroll
                for (int am = 0; am < 4; ++am)
                    acc[am][bn] = __builtin_amdgcn_mfma_f32_16x16x32_bf16(af[am], bfr, acc[am][bn], 0, 0, 0);
            }
            // counted barrier: retire B(+older c/stores), keep the 8 A-loads in flight
            asm volatile("s_waitcnt vmcnt(8)" ::: "memory");
            __builtin_amdgcn_s_barrier();
        }

        // ---- epilogue tile t ----
        float cn[4][2][4];
#pragma unroll
        for (int am = 0; am < 4; ++am)
#pragma unroll
            for (int hb = 0; hb < 2; ++hb)
#pragma unroll
                for (int r = 0; r < 4; ++r) {
                    float f  = fsig(acc[am][0 + hb][r] + bfb[hb]);
                    float i  = fsig(acc[am][2 + hb][r] + bib[hb]);
                    float ct = ftanh(acc[am][4 + hb][r] + bcb[hb]);
                    float cv = f * creg[am][hb][r] + i * ct;
                    cn[am][hb][r] = cv;
                    int blk  = ((wm * 4 + am) * 4 + wn);
                    int slot = (hb * 2 + (l15 >> 3)) * 16 + (lg * 4 + r);
                    *(unsigned short*)(lds + 98304 + blk * 1024 + slot * 16 + (l15 & 7) * 2) = f2bf(cv);
                }
        // lgkmcnt-only barrier: cn visible, A-prefetch for next tile stays in flight
        asm volatile("s_waitcnt lgkmcnt(0)" ::: "memory");
        __builtin_amdgcn_s_barrier();

        // GEMM2: t2[128,128] = c_new @ Wch ; wave tile 64 rows x 32 cols
        f32x4 acc2[4][2];
#pragma unroll
        for (int a = 0; a < 4; ++a) { acc2[a][0] = {0.f,0.f,0.f,0.f}; acc2[a][1] = {0.f,0.f,0.f,0.f}; }
#pragma unroll
        for (int kt = 0; kt < 4; ++kt) {
            bf16x8 a2[4];
#pragma unroll
            for (int m = 0; m < 4; ++m)
                a2[m] = *(const bf16x8*)(lds + 98304 + ((wm * 4 + m) * 4 + kt) * 1024 + lane * 16);
#pragma unroll
            for (int n2 = 0; n2 < 2; ++n2) {
                bf16x8 b2 = *(const bf16x8*)(lds + 65536 + ((wn * 2 + n2) * 4 + kt) * 1024 + lane * 16);
#pragma unroll
                for (int m = 0; m < 4; ++m)
                    acc2[m][n2] = __builtin_amdgcn_mfma_f32_16x16x32_bf16(a2[m], b2, acc2[m][n2], 0, 0, 0);
            }
        }

        // h = o * tanh(t2 + bch); store h and c_new (fp32)
#pragma unroll
        for (int am = 0; am < 4; ++am)
#pragma unroll
            for (int hb = 0; hb < 2; ++hb)
#pragma unroll
                for (int r = 0; r < 4; ++r) {
                    long grow = m0 + wm * 64 + am * 16 + lg * 4 + r;
                    int col = wn * 32 + hb * 16 + l15;
                    float o  = fsig(acc[am][6 + hb][r] + bob[hb]);
                    float hv = o * ftanh(acc2[am][hb][r] + bchb[hb]);
                    hout[grow * 128 + col] = hv;
                    cout[grow * 128 + col] = cn[am][hb][r];
                }
        // re-zero gate accumulators for next tile
#pragma unroll
        for (int a = 0; a < 4; ++a)
#pragma unroll
            for (int b = 0; b < 8; ++b) acc[a][b] = {0.f, 0.f, 0.f, 0.f};
    }
}

extern "C" void kernel_launch(void* const* d_in, const int* in_sizes, int n_in,
                              void* d_out, int out_size, void* d_ws, size_t ws_size,
                              hipStream_t stream)
{
    const float* x   = (const float*)d_in[0];
    const float* h   = (const float*)d_in[1];
    const float* c   = (const float*)d_in[2];
    const float* Wf  = (const float*)d_in[3];
    const float* bf_ = (const float*)d_in[4];
    const float* Wi  = (const float*)d_in[5];
    const float* bi_ = (const float*)d_in[6];
    const float* Wc  = (const float*)d_in[7];
    const float* bc_ = (const float*)d_in[8];
    const float* Wo  = (const float*)d_in[9];
    const float* bo_ = (const float*)d_in[10];
    const float* Wch = (const float*)d_in[11];
    const float* bch = (const float*)d_in[12];

    unsigned short* WgF  = (unsigned short*)d_ws;         // 512*256 bf16 fragment-linear
    unsigned short* WchF = WgF + 512 * 256;               // 128*128 bf16 fragment-linear
    float* out = (float*)d_out;

    int nrows = in_sizes[0] / 128;                        // 262144

    prep_weights<<<dim3(72), dim3(256), 0, stream>>>(Wf, Wi, Wc, Wo, Wch, WgF, WchF);
    lstm_fused<<<dim3(256), dim3(512), 0, stream>>>(
        x, h, c, bf_, bi_, bc_, bo_, bch, WgF, WchF, out, nrows);
}

// Round 5
// 270.004 us; speedup vs baseline: 1.9447x; 1.9447x over previous
//
#include <hip/hip_runtime.h>
#include <hip/hip_bf16.h>

// LSTM block, fused. Inputs fp32, outputs fp32. bf16 MFMA internally.
// 256-thread blocks (4 waves), 64 rows each, 2 blocks/CU (64KB LDS, <=256 VGPR).
// Wave w owns the 64x128 gate tile for N'-group w (gate-interleaved permutation
// -> 4-gate elementwise is lane-local). A: global->reg (depth-2 dbuf), B: LDS
// dbuf via global_load_lds. Epilogue reuses B0 for Wch, B1 for c_new exchange.

typedef __attribute__((ext_vector_type(8))) short bf16x8;   // 8 bf16 = 4 VGPRs
typedef __attribute__((ext_vector_type(4))) float f32x4;

static __device__ __forceinline__ unsigned short f2bf(float f) {
    unsigned int u = __builtin_bit_cast(unsigned int, f);
    u += 0x7FFFu + ((u >> 16) & 1u);      // RNE
    return (unsigned short)(u >> 16);
}

static __device__ __forceinline__ bf16x8 cvt8(f32x4 a, f32x4 b) {
    union { bf16x8 v; unsigned short u[8]; } r;
    r.u[0] = f2bf(a[0]); r.u[1] = f2bf(a[1]); r.u[2] = f2bf(a[2]); r.u[3] = f2bf(a[3]);
    r.u[4] = f2bf(b[0]); r.u[5] = f2bf(b[1]); r.u[6] = f2bf(b[2]); r.u[7] = f2bf(b[3]);
    return r.v;
}

static __device__ __forceinline__ float fsig(float x) {
    float e = __builtin_amdgcn_exp2f(-1.44269504f * x);
    return __builtin_amdgcn_rcpf(1.0f + e);
}
static __device__ __forceinline__ float ftanh(float x) {
    float e = __builtin_amdgcn_exp2f(2.8853900818f * x);
    return 1.0f - 2.0f * __builtin_amdgcn_rcpf(e + 1.0f);
}

static __device__ __forceinline__ void gload16(const void* gsrc, void* ldst) {
    __builtin_amdgcn_global_load_lds(
        (const __attribute__((address_space(1))) unsigned int*)gsrc,
        (__attribute__((address_space(3))) unsigned int*)ldst,
        16, 0, 0);
}

// ---------------- weight prep: fragment-linear bf16 layouts (r3-proven) ----------------
__global__ void prep_weights(const float* __restrict__ Wf, const float* __restrict__ Wi,
                             const float* __restrict__ Wc, const float* __restrict__ Wo,
                             const float* __restrict__ Wch,
                             unsigned short* __restrict__ WgF,   // 512*256
                             unsigned short* __restrict__ WchF)  // 128*128
{
    int u = blockIdx.x * 256 + threadIdx.x;
    if (u < 16384) {
        int lane = u & 63, nb = (u >> 6) & 31, kc = u >> 11;
        int l15 = lane & 15, lg = lane >> 4;
        int np = nb * 16 + l15;                  // permuted col index
        int wv = np >> 7, g = (np >> 5) & 3, c5 = np & 31;
        int cg = wv * 32 + c5;                   // within-gate col
        int k0 = kc * 32 + lg * 8;
        const float* W = (g == 0) ? Wf : (g == 1) ? Wi : (g == 2) ? Wc : Wo;
        union { bf16x8 v; unsigned short s[8]; } r;
#pragma unroll
        for (int i = 0; i < 8; ++i) r.s[i] = f2bf(W[(size_t)(k0 + i) * 128 + cg]);
        *(bf16x8*)(WgF + (size_t)u * 8) = r.v;
    } else if (u < 16384 + 2048) {
        int u2 = u - 16384;
        int lane = u2 & 63, kt = (u2 >> 6) & 3, nb2 = u2 >> 8;
        int l15 = lane & 15, lg = lane >> 4;
        int n = nb2 * 16 + l15, k0 = kt * 32 + lg * 8;
        union { bf16x8 v; unsigned short s[8]; } r;
#pragma unroll
        for (int i = 0; i < 8; ++i) r.s[i] = f2bf(Wch[(size_t)(k0 + i) * 128 + n]);
        *(bf16x8*)(WchF + (size_t)u2 * 8) = r.v;
    }
}

// ---------------- fused kernel: 64 rows per 256-thread block ----------------
// LDS map (64 KB): B0 [0,32K) ; B1 [32K,64K).
// Epilogue reuse: Wch -> B0 (staged during chunk 7); c_ex 16KB -> B1.
__global__ __launch_bounds__(256, 2) void lstm_fused(
    const float* __restrict__ xg, const float* __restrict__ hg, const float* __restrict__ cg,
    const float* __restrict__ bfv, const float* __restrict__ biv,
    const float* __restrict__ bcv, const float* __restrict__ bov,
    const float* __restrict__ bchv,
    const unsigned short* __restrict__ WgF, const unsigned short* __restrict__ WchF,
    float* __restrict__ out, int nrows)
{
    __shared__ uint4 lds4[4096];                 // 64 KB
    char* lds = (char*)lds4;

    const int tid  = threadIdx.x;
    const int lane = tid & 63;
    const int wn   = tid >> 6;                   // 0..3 : N' group (128 of 512 cols)
    const int l15  = lane & 15;
    const int lg   = lane >> 4;
    const long m0  = (long)blockIdx.x * 64;

    float* hout = out;
    float* cout = out + (size_t)nrows * 128;

    // biases (lane-local cols: col = wn*32 + hb*16 + l15)
    float bfb[2], bib[2], bcb[2], bob[2], bchb[2];
#pragma unroll
    for (int hb = 0; hb < 2; ++hb) {
        int col = wn * 32 + hb * 16 + l15;
        bfb[hb] = bfv[col]; bib[hb] = biv[col]; bcb[hb] = bcv[col];
        bob[hb] = bov[col]; bchb[hb] = bchv[col];
    }

    // ---- prologue: B chunk 0 -> B0 (gload), A step 0 -> regs
#pragma unroll
    for (int j = 0; j < 8; ++j)
        gload16((const char*)WgF + j * 4096 + tid * 16, lds + j * 4096 + tid * 16);

    f32x4 araw[2][4][2];
#pragma unroll
    for (int am = 0; am < 4; ++am) {
        long row = m0 + am * 16 + l15;
        const f32x4* s = (const f32x4*)(xg + row * 128 + lg * 8);   // kc=0 cols in x
        araw[0][am][0] = s[0];
        araw[0][am][1] = s[1];
    }

    f32x4 acc[4][8];
#pragma unroll
    for (int a = 0; a < 4; ++a)
#pragma unroll
        for (int b = 0; b < 8; ++b) acc[a][b] = {0.f, 0.f, 0.f, 0.f};

    float creg[4][2][4];

    __syncthreads();                             // B0 + A0 landed

    // ---- GEMM1: 8 K-chunks of 32, B dbuf in LDS, A dbuf in regs
#pragma unroll
    for (int kc = 0; kc < 8; ++kc) {
        const int cur = kc & 1, nxt = cur ^ 1;
        if (kc < 7) {
            // B prefetch chunk kc+1 -> buf nxt
            const char* src = (const char*)WgF + (size_t)(kc + 1) * 32768;
            char* dst = lds + nxt * 32768;
#pragma unroll
            for (int j = 0; j < 8; ++j)
                gload16(src + j * 4096 + tid * 16, dst + j * 4096 + tid * 16);
            // A prefetch step kc+1
            int col = (kc + 1) * 32 + lg * 8;
            const float* g = (col < 128) ? (xg + col) : (hg + (col - 128));
#pragma unroll
            for (int am = 0; am < 4; ++am) {
                long row = m0 + am * 16 + l15;
                const f32x4* s = (const f32x4*)(g + row * 128);
                araw[nxt][am][0] = s[0];
                araw[nxt][am][1] = s[1];
            }
        } else {
            // chunk 7 computes from B1; B0 is free -> stage Wch; load c input
#pragma unroll
            for (int j = 0; j < 8; ++j)
                gload16((const char*)WchF + j * 4096 + tid * 16, lds + j * 4096 + tid * 16);
#pragma unroll
            for (int am = 0; am < 4; ++am)
#pragma unroll
                for (int hb = 0; hb < 2; ++hb)
#pragma unroll
                    for (int r = 0; r < 4; ++r) {
                        long grow = m0 + am * 16 + lg * 4 + r;
                        creg[am][hb][r] = cg[grow * 128 + wn * 32 + hb * 16 + l15];
                    }
        }
        // compute: cvt current A, MFMA against LDS B
        bf16x8 af[4];
#pragma unroll
        for (int am = 0; am < 4; ++am)
            af[am] = cvt8(araw[cur][am][0], araw[cur][am][1]);
        const char* bb = lds + cur * 32768 + wn * 8192;
#pragma unroll
        for (int bn = 0; bn < 8; ++bn) {
            bf16x8 bfr = *(const bf16x8*)(bb + bn * 1024 + lane * 16);
#pragma unroll
            for (int am = 0; am < 4; ++am)
                acc[am][bn] = __builtin_amdgcn_mfma_f32_16x16x32_bf16(af[am], bfr, acc[am][bn], 0, 0, 0);
        }
        __syncthreads();
    }

    // ---- elementwise: gates -> c_new (fp32 regs + bf16 exchange into B1 region)
    float cn[4][2][4];
#pragma unroll
    for (int am = 0; am < 4; ++am)
#pragma unroll
        for (int hb = 0; hb < 2; ++hb)
#pragma unroll
            for (int r = 0; r < 4; ++r) {
                float f  = fsig(acc[am][0 + hb][r] + bfb[hb]);
                float i  = fsig(acc[am][2 + hb][r] + bib[hb]);
                float ct = ftanh(acc[am][4 + hb][r] + bcb[hb]);
                float cv = f * creg[am][hb][r] + i * ct;
                cn[am][hb][r] = cv;
                int blk  = am * 4 + wn;                       // (row-blk, kt=wn)
                int slot = (hb * 2 + (l15 >> 3)) * 16 + (lg * 4 + r);
                *(unsigned short*)(lds + 32768 + blk * 1024 + slot * 16 + (l15 & 7) * 2) = f2bf(cv);
            }
    __syncthreads();                             // c_ex visible (Wch landed at loop's last barrier)

    // ---- GEMM2: t2[64,128] = c_new @ Wch ; wave tile 64 rows x 32 cols
    f32x4 acc2[4][2];
#pragma unroll
    for (int a = 0; a < 4; ++a) { acc2[a][0] = {0.f,0.f,0.f,0.f}; acc2[a][1] = {0.f,0.f,0.f,0.f}; }
#pragma unroll
    for (int kt = 0; kt < 4; ++kt) {
        bf16x8 a2[4];
#pragma unroll
        for (int m = 0; m < 4; ++m)
            a2[m] = *(const bf16x8*)(lds + 32768 + (m * 4 + kt) * 1024 + lane * 16);
#pragma unroll
        for (int n2 = 0; n2 < 2; ++n2) {
            bf16x8 b2 = *(const bf16x8*)(lds + ((wn * 2 + n2) * 4 + kt) * 1024 + lane * 16);
#pragma unroll
            for (int m = 0; m < 4; ++m)
                acc2[m][n2] = __builtin_amdgcn_mfma_f32_16x16x32_bf16(a2[m], b2, acc2[m][n2], 0, 0, 0);
        }
    }

    // ---- h = o * tanh(t2 + bch); store h and c_new (fp32, 64B-coalesced groups)
#pragma unroll
    for (int am = 0; am < 4; ++am)
#pragma unroll
        for (int hb = 0; hb < 2; ++hb)
#pragma unroll
            for (int r = 0; r < 4; ++r) {
                long grow = m0 + am * 16 + lg * 4 + r;
                int col = wn * 32 + hb * 16 + l15;
                float o  = fsig(acc[am][6 + hb][r] + bob[hb]);
                float hv = o * ftanh(acc2[am][hb][r] + bchb[hb]);
                hout[grow * 128 + col] = hv;
                cout[grow * 128 + col] = cn[am][hb][r];
            }
}

extern "C" void kernel_launch(void* const* d_in, const int* in_sizes, int n_in,
                              void* d_out, int out_size, void* d_ws, size_t ws_size,
                              hipStream_t stream)
{
    const float* x   = (const float*)d_in[0];
    const float* h   = (const float*)d_in[1];
    const float* c   = (const float*)d_in[2];
    const float* Wf  = (const float*)d_in[3];
    const float* bf_ = (const float*)d_in[4];
    const float* Wi  = (const float*)d_in[5];
    const float* bi_ = (const float*)d_in[6];
    const float* Wc  = (const float*)d_in[7];
    const float* bc_ = (const float*)d_in[8];
    const float* Wo  = (const float*)d_in[9];
    const float* bo_ = (const float*)d_in[10];
    const float* Wch = (const float*)d_in[11];
    const float* bch = (const float*)d_in[12];

    unsigned short* WgF  = (unsigned short*)d_ws;         // 512*256 bf16 fragment-linear
    unsigned short* WchF = WgF + 512 * 256;               // 128*128 bf16 fragment-linear
    float* out = (float*)d_out;

    int nrows = in_sizes[0] / 128;                        // 262144

    prep_weights<<<dim3(72), dim3(256), 0, stream>>>(Wf, Wi, Wc, Wo, Wch, WgF, WchF);
    lstm_fused<<<dim3(nrows / 64), dim3(256), 0, stream>>>(
        x, h, c, bf_, bi_, bc_, bo_, bch, WgF, WchF, out, nrows);
}